// Round 6
// baseline (280.736 us; speedup 1.0000x reference)
//
#include <hip/hip_runtime.h>
#include <hip/hip_bf16.h>

typedef unsigned short u16;
typedef unsigned int   u32;
typedef short bf16x8 __attribute__((ext_vector_type(8)));
typedef float f32x4  __attribute__((ext_vector_type(4)));

#define N_NODES  50000
#define N_EDGES  800000
#define DIM      64
#define N_GRAPHS 64
#define OUT_DIM  10
#define POOL_BLOCKS 256
#define POOL_CHUNK  ((N_NODES + POOL_BLOCKS - 1) / POOL_BLOCKS)   // 196

// bucket CSR build
#define BSHIFT 8
#define NBUCK  196          // ceil(50000/256)
#define BCAP   5000         // mean 4096, sd ~64 -> statically safe
#define EPB    2048
#define NBLK_A ((N_EDGES + EPB - 1) / EPB)   // 391

__device__ __forceinline__ u16 f2bf(float f) {
    u32 u = __float_as_uint(f);
    u32 r = (u + 0x7fffu + ((u >> 16) & 1u)) >> 16;
    return (u16)r;
}
__device__ __forceinline__ float bf_lo(u32 u) { return __uint_as_float(u << 16); }
__device__ __forceinline__ float bf_hi(u32 u) { return __uint_as_float(u & 0xffff0000u); }

// ---------------- bucketed CSR build ----------------
__global__ __launch_bounds__(256) void bucket_scatter(const int* __restrict__ src,
                                                      const int* __restrict__ dst,
                                                      int* __restrict__ bcur,
                                                      u32* __restrict__ bscratch) {
    __shared__ int hist[NBUCK];
    __shared__ int base[NBUCK];
    int t = threadIdx.x;
    for (int i = t; i < NBUCK; i += 256) hist[i] = 0;
    __syncthreads();
    int e0 = blockIdx.x * EPB;
    u32 packed[8];
    int bb[8];
    #pragma unroll
    for (int i = 0; i < 8; ++i) {
        int e = e0 + i * 256 + t;
        if (e < N_EDGES) {
            int d = dst[e], s = src[e];
            bb[i] = d >> BSHIFT;
            packed[i] = ((u32)s << BSHIFT) | (u32)(d & ((1 << BSHIFT) - 1));
            atomicAdd(&hist[bb[i]], 1);
        } else bb[i] = -1;
    }
    __syncthreads();
    for (int i = t; i < NBUCK; i += 256)
        base[i] = (hist[i] > 0) ? atomicAdd(&bcur[i], hist[i]) : 0;
    __syncthreads();
    #pragma unroll
    for (int i = 0; i < 8; ++i) {
        if (bb[i] >= 0) {
            int pos = atomicAdd(&base[bb[i]], 1);
            bscratch[bb[i] * BCAP + pos] = packed[i];
        }
    }
}

// per-bucket: bucket-prefix (internal), node count/scan in LDS, dense offs+csr
__global__ __launch_bounds__(256) void csr_build(const u32* __restrict__ bscratch,
                                                 const int* __restrict__ bcur,
                                                 int* __restrict__ offs,
                                                 int* __restrict__ csr) {
    __shared__ int cnt[256];
    __shared__ int sc[256];
    __shared__ int cur2[256];
    __shared__ int gb[256];
    int b = blockIdx.x, t = threadIdx.x;
    // prefix of bucket totals over buckets < b
    int vb = (t < b) ? bcur[t] : 0;
    gb[t] = vb;
    cnt[t] = 0;
    __syncthreads();
    for (int d = 1; d < 256; d <<= 1) {
        int tmp = (t >= d) ? gb[t - d] : 0;
        __syncthreads();
        gb[t] += tmp;
        __syncthreads();
    }
    int gbase = gb[255];
    int n_b = bcur[b];
    const u32* bp = bscratch + (size_t)b * BCAP;
    for (int i = t; i < n_b; i += 256) atomicAdd(&cnt[bp[i] & 255], 1);
    __syncthreads();
    int v = cnt[t];
    sc[t] = v;
    __syncthreads();
    for (int d = 1; d < 256; d <<= 1) {
        int tmp = (t >= d) ? sc[t - d] : 0;
        __syncthreads();
        sc[t] += tmp;
        __syncthreads();
    }
    int excl = sc[t] - v;
    int node = (b << BSHIFT) + t;
    if (node < N_NODES) offs[node] = gbase + excl;
    if (b == NBUCK - 1 && t == 0) offs[N_NODES] = N_EDGES;
    cur2[t] = gbase + excl;
    __syncthreads();
    for (int i = t; i < n_b; i += 256) {
        u32 p = bp[i];
        int pos = atomicAdd(&cur2[p & 255], 1);
        csr[pos] = (int)(p >> BSHIFT);
    }
}

// ---------------- precompute ----------------

__global__ __launch_bounds__(256) void convert_x(const float* __restrict__ x,
                                                 u16* __restrict__ hb) {
    int c = blockIdx.x * 256 + threadIdx.x;
    if (c >= N_NODES * 8) return;
    const float* src = x + (size_t)c * 8;
    float4 f0 = *(const float4*)src;
    float4 f1 = *(const float4*)(src + 4);
    uint4 pk;
    pk.x = (u32)f2bf(f0.x) | ((u32)f2bf(f0.y) << 16);
    pk.y = (u32)f2bf(f0.z) | ((u32)f2bf(f0.w) << 16);
    pk.z = (u32)f2bf(f1.x) | ((u32)f2bf(f1.y) << 16);
    pk.w = (u32)f2bf(f1.z) | ((u32)f2bf(f1.w) << 16);
    *(uint4*)(hb + (size_t)c * 8) = pk;
}

// transpose W -> bf16 Wtb[l][m*64+col][k]; tail blocks zero gsums
__global__ __launch_bounds__(256) void prep_w(
    const float* __restrict__ Wq, const float* __restrict__ Wk,
    const float* __restrict__ Wv, const float* __restrict__ Ws,
    u16* __restrict__ Wtb, float* __restrict__ gsums) {
    int id = blockIdx.x * 256 + threadIdx.x;
    if (id < 8192) {
        int kc  = id & 7;
        int col = (id >> 3) & 63;
        int m   = (id >> 9) & 3;
        int l   = id >> 11;
        const float* W = ((m == 0) ? Wq : (m == 1) ? Wk : (m == 2) ? Wv : Ws) + l * 4096;
        u16 b[8];
        #pragma unroll
        for (int j = 0; j < 8; ++j) b[j] = f2bf(W[(kc * 8 + j) * 64 + col]);
        uint4 pk;
        pk.x = (u32)b[0] | ((u32)b[1] << 16);
        pk.y = (u32)b[2] | ((u32)b[3] << 16);
        pk.z = (u32)b[4] | ((u32)b[5] << 16);
        pk.w = (u32)b[6] | ((u32)b[7] << 16);
        *(uint4*)(Wtb + ((size_t)(l * 256 + m * 64 + col)) * 64 + kc * 8) = pk;
    } else if (id < 8192 + N_GRAPHS * DIM) {
        gsums[id - 8192] = 0.f;
    }
}

// ---------------- LDS-free MFMA GEMM: q bf16, k|v interleaved bf16, s-path f32 ----------------
// 256 thr = 4 waves; wave w computes matrix w over 64 nodes; fragments direct from global.
__global__ __launch_bounds__(256) void gemm_mfma(
    const u16* __restrict__ hb, const u16* __restrict__ Wtb,
    const float* __restrict__ bq, const float* __restrict__ bk,
    const float* __restrict__ bv, const float* __restrict__ bs,
    u16* __restrict__ q, u16* __restrict__ kv, float* __restrict__ sbuf) {
    int t = threadIdx.x;
    int wave = t >> 6, lane = t & 63;
    int nb = blockIdx.x * 64;
    int lr = lane & 15, lg4 = lane >> 4;

    const float* bm = (wave == 0) ? bq : (wave == 1) ? bk : (wave == 2) ? bv : bs;

    f32x4 acc[4][4];
    #pragma unroll
    for (int ct = 0; ct < 4; ++ct) {
        float bval = bm[ct * 16 + lr];
        #pragma unroll
        for (int rt = 0; rt < 4; ++rt) acc[rt][ct] = (f32x4){bval, bval, bval, bval};
    }

    const u16* wb = Wtb + (size_t)wave * 64 * 64;
    #pragma unroll
    for (int s = 0; s < 2; ++s) {
        bf16x8 af[4], bfr[4];
        #pragma unroll
        for (int rt = 0; rt < 4; ++rt)
            af[rt] = *(const bf16x8*)(hb + (size_t)(nb + rt * 16 + lr) * 64 + s * 32 + lg4 * 8);
        #pragma unroll
        for (int ct = 0; ct < 4; ++ct)
            bfr[ct] = *(const bf16x8*)(wb + (size_t)(ct * 16 + lr) * 64 + s * 32 + lg4 * 8);
        #pragma unroll
        for (int rt = 0; rt < 4; ++rt)
            #pragma unroll
            for (int ct = 0; ct < 4; ++ct)
                acc[rt][ct] = __builtin_amdgcn_mfma_f32_16x16x32_bf16(
                    af[rt], bfr[ct], acc[rt][ct], 0, 0, 0);
    }

    // D layout: col = ct*16+lr, row = rt*16 + lg4*4 + r
    #pragma unroll
    for (int rt = 0; rt < 4; ++rt) {
        #pragma unroll
        for (int r = 0; r < 4; ++r) {
            int row = rt * 16 + lg4 * 4 + r;
            int node = nb + row;
            if (node >= N_NODES) continue;
            if (wave == 0) {
                #pragma unroll
                for (int ct = 0; ct < 4; ++ct)
                    q[(size_t)node * 64 + ct * 16 + lr] = f2bf(acc[rt][ct][r]);
            } else if (wave == 1) {
                #pragma unroll
                for (int ct = 0; ct < 4; ++ct) {
                    int slot = (2 * ct + (lr >> 3)) * 16 + (lr & 7);
                    kv[(size_t)node * 128 + slot] = f2bf(acc[rt][ct][r]);
                }
            } else if (wave == 2) {
                #pragma unroll
                for (int ct = 0; ct < 4; ++ct) {
                    int slot = (2 * ct + (lr >> 3)) * 16 + (lr & 7) + 8;
                    kv[(size_t)node * 128 + slot] = f2bf(acc[rt][ct][r]);
                }
            } else {
                #pragma unroll
                for (int ct = 0; ct < 4; ++ct)
                    sbuf[(size_t)node * 64 + ct * 16 + lr] = acc[rt][ct][r];
            }
        }
    }
}

// ---------------- edge attention: deferred-max online softmax, pipelined gathers ----------------
// wave per dst; 8 groups x 8 lanes; kv interleaved: lane lg reads 32B at node*256+lg*32.
__global__ __launch_bounds__(256) void edge_attn(
    const u16* __restrict__ q, const u16* __restrict__ kv,
    const int* __restrict__ offs, const int* __restrict__ csr_src,
    const float* __restrict__ sbuf,
    float* __restrict__ hfin, u16* __restrict__ hb, int last) {
    int wave = threadIdx.x >> 6, lane = threadIdx.x & 63;
    int n = blockIdx.x * 4 + wave;
    int g = lane >> 3, lg = lane & 7;
    uint4 qu = *(const uint4*)(q + (size_t)n * 64 + lg * 8);
    float q0 = bf_lo(qu.x), q1 = bf_hi(qu.x);
    float q2 = bf_lo(qu.y), q3 = bf_hi(qu.y);
    float q4 = bf_lo(qu.z), q5 = bf_hi(qu.z);
    float q6 = bf_lo(qu.w), q7 = bf_hi(qu.w);
    int e0 = offs[n], e1 = offs[n + 1];
    float m = -3.0e38f, z = 0.f;
    float a8[8] = {0.f, 0.f, 0.f, 0.f, 0.f, 0.f, 0.f, 0.f};
    int e = e0 + g;
    bool valid = (e < e1);
    int sg = valid ? csr_src[e] : 0;
    while (valid) {
        const u16* kvp = kv + (size_t)sg * 128 + lg * 16;
        uint4 ku = *(const uint4*)kvp;
        uint4 vu = *(const uint4*)(kvp + 8);
        int en = e + 8;
        bool vnext = (en < e1);
        int sgn = vnext ? csr_src[en] : 0;       // prefetch next index
        float d0 = bf_lo(ku.x) * q0;
        d0 = fmaf(bf_hi(ku.x), q1, d0);
        d0 = fmaf(bf_lo(ku.y), q2, d0);
        d0 = fmaf(bf_hi(ku.y), q3, d0);
        float d1 = bf_lo(ku.z) * q4;
        d1 = fmaf(bf_hi(ku.z), q5, d1);
        d1 = fmaf(bf_lo(ku.w), q6, d1);
        d1 = fmaf(bf_hi(ku.w), q7, d1);
        float d = d0 + d1;
        d += __shfl_xor(d, 1);
        d += __shfl_xor(d, 2);
        d += __shfl_xor(d, 4);
        float alpha = d * 0.125f;                 // 1/sqrt(64)
        float diff = alpha - m;
        if (__builtin_expect(diff > 25.f, 0)) {   // rare rescale
            float c = __expf(-diff);
            z *= c;
            #pragma unroll
            for (int j = 0; j < 8; ++j) a8[j] *= c;
            m = alpha;
            diff = 0.f;
        }
        float p = __expf(diff);
        z += p;
        a8[0] = fmaf(p, bf_lo(vu.x), a8[0]);
        a8[1] = fmaf(p, bf_hi(vu.x), a8[1]);
        a8[2] = fmaf(p, bf_lo(vu.y), a8[2]);
        a8[3] = fmaf(p, bf_hi(vu.y), a8[3]);
        a8[4] = fmaf(p, bf_lo(vu.z), a8[4]);
        a8[5] = fmaf(p, bf_hi(vu.z), a8[5]);
        a8[6] = fmaf(p, bf_lo(vu.w), a8[6]);
        a8[7] = fmaf(p, bf_hi(vu.w), a8[7]);
        e = en; valid = vnext; sg = sgn;
    }
    // combine 8 groups (m is each group's exp-offset; math exact)
    float M = m;
    M = fmaxf(M, __shfl_xor(M, 8));
    M = fmaxf(M, __shfl_xor(M, 16));
    M = fmaxf(M, __shfl_xor(M, 32));
    float s = __expf(m - M);
    z *= s;
    z += __shfl_xor(z, 8); z += __shfl_xor(z, 16); z += __shfl_xor(z, 32);
    #pragma unroll
    for (int j = 0; j < 8; ++j) {
        float a = a8[j] * s;
        a += __shfl_xor(a, 8); a += __shfl_xor(a, 16); a += __shfl_xor(a, 32);
        a8[j] = a;
    }
    if (g == 0) {
        float invz = 1.f / (z + 1e-16f);
        const float* sp = sbuf + (size_t)n * 64 + lg * 8;
        float4 s0 = *(const float4*)sp;
        float4 s1 = *(const float4*)(sp + 4);
        float r0 = s0.x + a8[0] * invz;
        float r1 = s0.y + a8[1] * invz;
        float r2 = s0.z + a8[2] * invz;
        float r3 = s0.w + a8[3] * invz;
        float r4 = s1.x + a8[4] * invz;
        float r5 = s1.y + a8[5] * invz;
        float r6 = s1.z + a8[6] * invz;
        float r7 = s1.w + a8[7] * invz;
        if (last) {
            float* hp = hfin + (size_t)n * 64 + lg * 8;
            *(float4*)hp = make_float4(r0, r1, r2, r3);
            *(float4*)(hp + 4) = make_float4(r4, r5, r6, r7);
        } else {
            uint4 pk;
            pk.x = (u32)f2bf(r0) | ((u32)f2bf(r1) << 16);
            pk.y = (u32)f2bf(r2) | ((u32)f2bf(r3) << 16);
            pk.z = (u32)f2bf(r4) | ((u32)f2bf(r5) << 16);
            pk.w = (u32)f2bf(r6) | ((u32)f2bf(r7) << 16);
            *(uint4*)(hb + (size_t)n * 64 + lg * 8) = pk;
        }
    }
}

// ---------------- pooling ----------------
__global__ __launch_bounds__(256) void pool_sums(const float* __restrict__ h,
                                                 const int* __restrict__ batch,
                                                 float* __restrict__ gsums) {
    int b = blockIdx.x, t = threadIdx.x;
    int d = t & 63, sub = t >> 6;
    int lo = b * POOL_CHUNK;
    int hi = lo + POOL_CHUNK;
    if (hi > N_NODES) hi = N_NODES;
    float acc = 0.f;
    int curg = -1;
    for (int n = lo + sub; n < hi; n += 4) {
        int g = batch[n];
        if (g != curg) {
            if (curg >= 0) atomicAdd(&gsums[curg * 64 + d], acc);
            acc = 0.f;
            curg = g;
        }
        acc += h[(size_t)n * 64 + d];
    }
    if (curg >= 0) atomicAdd(&gsums[curg * 64 + d], acc);
}

__device__ __forceinline__ int lbound(const int* a, int n, int key) {
    int lo = 0, hi = n;
    while (lo < hi) {
        int mid = (lo + hi) >> 1;
        if (a[mid] < key) lo = mid + 1; else hi = mid;
    }
    return lo;
}

__global__ __launch_bounds__(256) void finalize(const float* __restrict__ gsums,
                                                const int* __restrict__ batch,
                                                const float* __restrict__ Wf,
                                                const float* __restrict__ bf,
                                                float* __restrict__ out) {
    __shared__ float pl[N_GRAPHS][DIM];
    __shared__ int bnd[N_GRAPHS + 1];
    int t = threadIdx.x;
    if (t <= N_GRAPHS) bnd[t] = (t == N_GRAPHS) ? N_NODES : lbound(batch, N_NODES, t);
    __syncthreads();
    for (int i = t; i < N_GRAPHS * DIM; i += 256) {
        int g = i >> 6;
        int cnt = bnd[g + 1] - bnd[g];
        pl[g][i & 63] = gsums[i] / (float)(cnt > 1 ? cnt : 1);
    }
    __syncthreads();
    for (int i = t; i < N_GRAPHS * OUT_DIM; i += 256) {
        int g = i / OUT_DIM, o = i % OUT_DIM;
        float acc = bf[o];
        #pragma unroll
        for (int d = 0; d < DIM; ++d) acc = fmaf(pl[g][d], Wf[d * OUT_DIM + o], acc);
        out[i] = acc;
    }
}

// ---------------- launch ----------------
extern "C" void kernel_launch(void* const* d_in, const int* in_sizes, int n_in,
                              void* d_out, int out_size, void* d_ws, size_t ws_size,
                              hipStream_t stream) {
    const float* x    = (const float*)d_in[0];
    const int*   ei   = (const int*)d_in[1];
    const int*   batch= (const int*)d_in[2];
    const float* Wq   = (const float*)d_in[3];
    const float* bq   = (const float*)d_in[4];
    const float* Wk   = (const float*)d_in[5];
    const float* bk   = (const float*)d_in[6];
    const float* Wv   = (const float*)d_in[7];
    const float* bv   = (const float*)d_in[8];
    const float* Ws   = (const float*)d_in[9];
    const float* bs   = (const float*)d_in[10];
    const float* Wf   = (const float*)d_in[11];
    const float* bf   = (const float*)d_in[12];
    float* out = (float*)d_out;

    char* ws = (char*)d_ws;
    u16*   qb16 = (u16*)  (ws + 0);            //  6.4 MB
    u16*   kvb  = (u16*)  (ws + 6400000);      // 12.8 MB interleaved k|v
    u16*   hb   = (u16*)  (ws + 19200000);     //  6.41 MB (+64-row slack for OOB frag reads)
    float* sbuf = (float*)(ws + 25608192);     // 12.8 MB (s-path f32, reused per layer)
    float* hfin = (float*)(ws + 38408192);     // 12.8 MB (final layer f32)
    u16*   Wtb  = (u16*)  (ws + 51208192);     //  256 KB
    int*   csr  = (int*)  (ws + 51470336);     //  3.2 MB
    int*   offs = (int*)  (ws + 54670336);     //  200 KB
    u32*   bscr = (u32*)  (ws + 54870352);     //  3.92 MB
    int*   bcur = (int*)  (ws + 58790352);     //  1 KB
    float* gsums= (float*)(ws + 58791376);     //  16 KB

    const int* srcI = ei;
    const int* dstI = ei + N_EDGES;

    hipMemsetAsync(bcur, 0, NBUCK * sizeof(int), stream);

    bucket_scatter<<<NBLK_A, 256, 0, stream>>>(srcI, dstI, bcur, bscr);
    csr_build<<<NBUCK, 256, 0, stream>>>(bscr, bcur, offs, csr);

    convert_x<<<(N_NODES * 8 + 255) / 256, 256, 0, stream>>>(x, hb);
    prep_w<<<48, 256, 0, stream>>>(Wq, Wk, Wv, Ws, Wtb, gsums);

    for (int l = 0; l < 4; ++l) {
        gemm_mfma<<<(N_NODES + 63) / 64, 256, 0, stream>>>(
            hb, Wtb + (size_t)l * 16384,
            bq + l * 64, bk + l * 64, bv + l * 64, bs + l * 64,
            qb16, kvb, sbuf);
        edge_attn<<<N_NODES / 4, 256, 0, stream>>>(
            qb16, kvb, offs, csr, sbuf, hfin, hb, (l == 3) ? 1 : 0);
    }
    pool_sums<<<POOL_BLOCKS, 256, 0, stream>>>(hfin, batch, gsums);
    finalize<<<1, 256, 0, stream>>>(gsums, batch, Wf, bf, out);
}